// Round 8
// baseline (315.995 us; speedup 1.0000x reference)
//
#include <hip/hip_runtime.h>

#define MCW_EPS 1e-32f

constexpr int NRED = 64;   // number of stage-2 groups

// ---------------------------------------------------------------------------
// R8: ONE fused persistent kernel.
// Main loop = R3's proven engine (simplest of three structures that all tied
// at ~41us / 3.3 TB/s: R3 depth-1 compiler-scheduled, R4 reg-pipeline, R7
// depth-3 global_load_lds -> streaming is at the pattern ceiling). Remaining
// overhead was structural: 2 extra launches + serial reduce/fin (~3-6us).
// Fusion via fenced last-block-done reduction, two levels:
//   level 1: blocks of group g (grpSize consecutive blockIdx) write partials,
//            __threadfence, atomicAdd(counters[g]); the last one reduces the
//            group's grpSize partial records -> Q[g] (~98KB read, overlaps
//            other blocks' main loops).
//   level 2: group-winners atomicAdd(counters[NRED]); the last one folds the
//            NRED Q-records + P_lg and writes the 2 outputs.
// Deterministic: every sum is over a fixed set in a fixed order. Cross-XCD
// visibility: release fence before each atomic, acquire fence after winning
// (standard CUB DeviceReduce pattern; atomics are device-scope by default).
// ---------------------------------------------------------------------------
__global__ __launch_bounds__(256, 8) void mcwauc_fused(
    const float* __restrict__ x_, const float* __restrict__ l_,
    int rowGroups, int grpSize, int G,
    float* __restrict__ P_sp, float* __restrict__ P_sn,
    float* __restrict__ P_np, float* __restrict__ P_lg,
    float* __restrict__ Q_sp, float* __restrict__ Q_sn,
    float* __restrict__ Q_np,
    unsigned int* __restrict__ counters,
    float* __restrict__ out, int B)
{
    const int t       = threadIdx.x;
    const int lane_rg = t >> 6;          // which of 4 rows in the row-group
    const int c0      = (t & 63) << 2;   // base column (4 consecutive cols)
    const size_t laneOff = (size_t)lane_rg * 256 + c0;

    float sp[4] = {0.f, 0.f, 0.f, 0.f};
    float sn[4] = {0.f, 0.f, 0.f, 0.f};
    float np[4] = {0.f, 0.f, 0.f, 0.f};
    float lp = 0.f, ln = 0.f;

    // ---- streaming main loop (R3 engine, verbatim) ----
    constexpr int U = 2;
    const int stride = gridDim.x * U;
    for (int rg0 = blockIdx.x * U; rg0 < rowGroups; rg0 += stride) {
        float4 xv[U], lv[U];
        #pragma unroll
        for (int u = 0; u < U; ++u) {
            const size_t idx = (size_t)(rg0 + u) * 1024 + laneOff;
            xv[u] = *reinterpret_cast<const float4*>(x_ + idx);
            lv[u] = *reinterpret_cast<const float4*>(l_ + idx);
        }
        #pragma unroll
        for (int u = 0; u < U; ++u) {
            #pragma unroll
            for (int k = 0; k < 4; ++k) {
                const float xw = (&xv[u].x)[k];
                const float lw = (&lv[u].x)[k];      // exactly 0.0f or 1.0f
                const float e  = __expf(-xw);
                const float s  = __builtin_amdgcn_rcpf(1.f + e);  // sigmoid
                const float s1 = e * s;              // 1 - sigmoid, no cancel
                const float sel = (lw != 0.f) ? s : s1;
                const float lg  = __logf(sel + MCW_EPS);
                sp[k] = fmaf(lw, s, sp[k]);
                sn[k] += s - lw * s;
                np[k] += lw;
                lp    = fmaf(lw, lg, lp);
                ln   += lg - lw * lg;
            }
        }
    }

    // ---- block epilogue: one 4KB LDS buffer reused 3x ----
    __shared__ float red[4][256];
    __shared__ float wl[2][4];

    #pragma unroll
    for (int o = 32; o > 0; o >>= 1) {
        lp += __shfl_down(lp, o);
        ln += __shfl_down(ln, o);
    }
    if ((t & 63) == 0) { wl[0][lane_rg] = lp; wl[1][lane_rg] = ln; }

    #pragma unroll
    for (int k = 0; k < 4; ++k) red[lane_rg][c0 + k] = sp[k];
    __syncthreads();
    const float a = red[0][t] + red[1][t] + red[2][t] + red[3][t];
    __syncthreads();
    #pragma unroll
    for (int k = 0; k < 4; ++k) red[lane_rg][c0 + k] = sn[k];
    __syncthreads();
    const float b = red[0][t] + red[1][t] + red[2][t] + red[3][t];
    __syncthreads();
    #pragma unroll
    for (int k = 0; k < 4; ++k) red[lane_rg][c0 + k] = np[k];
    __syncthreads();
    const float d = red[0][t] + red[1][t] + red[2][t] + red[3][t];

    const int bid = blockIdx.x;
    const size_t base = (size_t)bid * 256;
    P_sp[base + t] = a;
    P_sn[base + t] = b;
    P_np[base + t] = d;
    if (t == 0) {
        P_lg[2 * bid + 0] = wl[0][0] + wl[0][1] + wl[0][2] + wl[0][3];
        P_lg[2 * bid + 1] = wl[1][0] + wl[1][1] + wl[1][2] + wl[1][3];
    }

    // ---- level-1 protocol: last block of group reduces the group ----
    const int g = bid / grpSize;
    __shared__ unsigned rank1;
    __threadfence();                              // release partials
    if (t == 0) rank1 = atomicAdd(&counters[g], 1u);
    __syncthreads();
    if (rank1 != (unsigned)(grpSize - 1)) return; // whole block uniform

    __threadfence();                              // acquire group partials
    {
        const int pr = t >> 6;
        const int c4 = (t & 63) << 2;
        float4 qa = {0.f, 0.f, 0.f, 0.f}, qb = qa, qd = qa;
        for (int p = pr; p < grpSize; p += 4) {
            const size_t off = ((size_t)g * grpSize + p) * 256 + c4;
            const float4 va = *reinterpret_cast<const float4*>(P_sp + off);
            const float4 vb = *reinterpret_cast<const float4*>(P_sn + off);
            const float4 vd = *reinterpret_cast<const float4*>(P_np + off);
            qa.x += va.x; qa.y += va.y; qa.z += va.z; qa.w += va.w;
            qb.x += vb.x; qb.y += vb.y; qb.z += vb.z; qb.w += vb.w;
            qd.x += vd.x; qd.y += vd.y; qd.z += vd.z; qd.w += vd.w;
        }
        __shared__ float4 ra[4][64], rb[4][64], rd[4][64];
        ra[pr][t & 63] = qa; rb[pr][t & 63] = qb; rd[pr][t & 63] = qd;
        __syncthreads();
        if (pr == 0) {
            #pragma unroll
            for (int r = 1; r < 4; ++r) {
                const float4 va = ra[r][t], vb = rb[r][t], vd = rd[r][t];
                qa.x += va.x; qa.y += va.y; qa.z += va.z; qa.w += va.w;
                qb.x += vb.x; qb.y += vb.y; qb.z += vb.z; qb.w += vb.w;
                qd.x += vd.x; qd.y += vd.y; qd.z += vd.z; qd.w += vd.w;
            }
            const size_t q = (size_t)g * 256 + c4;
            *reinterpret_cast<float4*>(Q_sp + q) = qa;
            *reinterpret_cast<float4*>(Q_sn + q) = qb;
            *reinterpret_cast<float4*>(Q_np + q) = qd;
        }
        __syncthreads();
    }

    // ---- level-2 protocol: last group-winner finalizes ----
    __shared__ unsigned rank2;
    __threadfence();                              // release Q[g]
    if (t == 0) rank2 = atomicAdd(&counters[NRED], 1u);
    __syncthreads();
    if (rank2 != (unsigned)(NRED - 1)) return;

    __threadfence();                              // acquire all Q + P_lg
    {
        const int c = t;
        float fa = 0.f, fb = 0.f, fd = 0.f;
        #pragma unroll 8
        for (int j = 0; j < NRED; ++j) {
            const size_t off = (size_t)j * 256 + c;
            fa += Q_sp[off];
            fb += Q_sn[off];
            fd += Q_np[off];
        }
        float flp = 0.f, fln = 0.f;
        for (int p = c; p < G; p += 256) {
            flp += P_lg[2 * p + 0];
            fln += P_lg[2 * p + 1];
        }

        const float npv = fd;
        const float nnv = (float)B - npv;
        const float mp  = fa / fmaxf(npv, 1.f);
        const float mn  = fb / fmaxf(nnv, 1.f);

        float pen;
        if (npv > 0.f && nnv > 0.f)      pen = 1.f - mp + mn;
        else if (npv == 0.f)             pen = 1.f + mn;
        else                             pen = 1.f - mp;

        float psum = pen, csum = npv;
        #pragma unroll
        for (int o = 32; o > 0; o >>= 1) {
            psum += __shfl_down(psum, o);
            csum += __shfl_down(csum, o);
            flp  += __shfl_down(flp, o);
            fln  += __shfl_down(fln, o);
        }
        __shared__ float s4[4][4];
        if ((c & 63) == 0) {
            s4[0][c >> 6] = psum;
            s4[1][c >> 6] = csum;
            s4[2][c >> 6] = flp;
            s4[3][c >> 6] = fln;
        }
        __syncthreads();

        if (c == 255) out[1] = 0.1f * pen;   // penalty of the LAST category
        if (c == 0) {
            const double pensum = (double)s4[0][0] + s4[0][1] + s4[0][2] + s4[0][3];
            const double numP   = (double)s4[1][0] + s4[1][1] + s4[1][2] + s4[1][3];
            const double L0     = (double)s4[2][0] + s4[2][1] + s4[2][2] + s4[2][3];
            const double L1     = (double)s4[3][0] + s4[3][1] + s4[3][2] + s4[3][3];
            const double total  = (double)B * 256.0;
            const double aP = numP / total;
            const double aN = 1.0 - aP;
            const double cel = -aN * (L0 / total) - aP * (L1 / total);
            out[0] = (float)(cel + 0.1 * (pensum / 256.0));
        }
    }
}

extern "C" void kernel_launch(void* const* d_in, const int* in_sizes, int n_in,
                              void* d_out, int out_size, void* d_ws, size_t ws_size,
                              hipStream_t stream) {
    const float* x = (const float*)d_in[0];
    const float* l = (const float*)d_in[1];
    const int n = in_sizes[0];
    const int B = n / 256;
    const int rowGroups = B / 4;           // B = 65536 -> 16384

    // G = grid (power of two, multiple of NRED), sized to ws.
    int G = 2048;                          // 8 blocks/CU
    auto need = [](int g) -> size_t {
        return (size_t)g * 768 * sizeof(float)       // P_sp/sn/np
             + (size_t)g * 2 * sizeof(float)         // P_lg
             + (size_t)NRED * 768 * sizeof(float)    // Q_sp/sn/np
             + (size_t)(NRED + 1) * sizeof(unsigned);
    };
    while (G > NRED && need(G) > ws_size) G >>= 1;
    const int grpSize = G / NRED;

    float* P_sp = (float*)d_ws;
    float* P_sn = P_sp + (size_t)G * 256;
    float* P_np = P_sn + (size_t)G * 256;
    float* P_lg = P_np + (size_t)G * 256;
    float* Q_sp = P_lg + (size_t)G * 2;
    float* Q_sn = Q_sp + (size_t)NRED * 256;
    float* Q_np = Q_sn + (size_t)NRED * 256;
    unsigned* counters = (unsigned*)(Q_np + (size_t)NRED * 256);

    // zero the completion counters every call (graph-safe async memset)
    hipMemsetAsync(counters, 0, (NRED + 1) * sizeof(unsigned), stream);

    mcwauc_fused<<<G, 256, 0, stream>>>(x, l, rowGroups, grpSize, G,
                                        P_sp, P_sn, P_np, P_lg,
                                        Q_sp, Q_sn, Q_np,
                                        counters, (float*)d_out, B);
}

// Round 9
// 38.403 us; speedup vs baseline: 8.2284x; 8.2284x over previous
//
#include <hip/hip_runtime.h>

#define MCW_EPS 1e-32f

constexpr int NRED = 64;   // stage-2 reduction blocks

typedef __attribute__((address_space(3))) float lds_f;
typedef const __attribute__((address_space(1))) float glb_f;

// ---------------------------------------------------------------------------
// R9 = R7 verbatim (revert of R8's fused-persistent experiment).
// R8 lesson: per-block __threadfence() on gfx950 = L2 writeback per call;
// 2048 of them cost ~0.2ms. Kernel-launch boundaries are the cheap cross-XCD
// sync. The 3-dispatch structure below is the best measured (38.9us), with
// the main loop at the ~3.3 TB/s read-path ceiling (R3/R4/R7 all tie there).
//
// Stage 1: stream output+labels once, deep prefetch via global_load_lds
// (direct-to-LDS DMA, no VGPR dest -> depth-3 pipeline, no reg-alloc hazard).
// Per wave: private slab of 3 bufs x 2KB (1KB x + 1KB l). No barriers in the
// loop (wave-private). Counted s_waitcnt vmcnt(4) per iter, sched_barrier(0)
// after each wait (rule #18).
// Layout: row-major [B,256]. Rowgroup = 4 rows = 1024 floats. Wave w covers
// floats [w*256,(w+1)*256) of each rowgroup; lane ln takes 16B at ln*4.
// Thread t = 64w+ln -> row w, cols 4*ln..+3. Chunk i of block b = rowgroup
// b + i*gridDim.x.
// ---------------------------------------------------------------------------
__global__ __launch_bounds__(256) void mcwauc_main(
    const float* __restrict__ x_, const float* __restrict__ l_,
    int rowGroups,
    float* __restrict__ P_sp, float* __restrict__ P_sn,
    float* __restrict__ P_np, float* __restrict__ P_lg)
{
    const int t   = threadIdx.x;
    const int wv  = t >> 6;            // wave id 0..3 (= row in rowgroup)
    const int ln  = t & 63;            // lane
    const int c0  = ln << 2;           // base column (4 consecutive cols)
    const int bid = blockIdx.x;
    const int gsz = gridDim.x;

    __shared__ float slab[6144];       // 4 waves x 3 bufs x 512 floats = 24KB
    __shared__ float wl[2][4];
    const int waveBase = wv * 1536;    // floats
    const int wvOff    = wv << 8;      // wave's float offset within rowgroup

    float sp[4] = {0.f, 0.f, 0.f, 0.f};
    float ts[4] = {0.f, 0.f, 0.f, 0.f};
    float np[4] = {0.f, 0.f, 0.f, 0.f};
    float lp = 0.f, lsum = 0.f;

    int nCh = 0;
    if (bid < rowGroups)
        nCh = (rowGroups - bid + gsz - 1) / gsz;

#define MCW_STAGE(CI, BO)                                                     \
    do {                                                                      \
        const size_t goff = ((size_t)bid + (size_t)(CI) * gsz) * 1024         \
                          + wvOff + (ln << 2);                                \
        lds_f* _d = (lds_f*)(slab + waveBase + (BO) * 512);                   \
        __builtin_amdgcn_global_load_lds((glb_f*)(x_ + goff), _d,       16, 0, 0); \
        __builtin_amdgcn_global_load_lds((glb_f*)(l_ + goff), _d + 256, 16, 0, 0); \
    } while (0)

#define MCW_WAITV(N) do {                                                     \
        asm volatile("s_waitcnt vmcnt(" #N ")" ::: "memory");                 \
        __builtin_amdgcn_sched_barrier(0); } while (0)
#define MCW_WAITL do {                                                        \
        asm volatile("s_waitcnt lgkmcnt(0)" ::: "memory");                    \
        __builtin_amdgcn_sched_barrier(0); } while (0)

    // prologue: fill the pipe (up to 3 chunks in flight)
    if (nCh > 0) MCW_STAGE(0, 0);
    if (nCh > 1) MCW_STAGE(1, 1);
    if (nCh > 2) MCW_STAGE(2, 2);

    int bo = 0;
    for (int i = 0; i < nCh; ++i) {
        const int rem = nCh - i;                    // wave-uniform
        if (rem >= 3)      { MCW_WAITV(4); }        // oldest of 3 landed
        else if (rem == 2) { MCW_WAITV(2); }
        else               { MCW_WAITV(0); }

        const float4 xv = *reinterpret_cast<const float4*>(
            &slab[waveBase + bo * 512 + c0]);
        const float4 lv = *reinterpret_cast<const float4*>(
            &slab[waveBase + bo * 512 + 256 + c0]);
        MCW_WAITL;                                  // reads landed in regs

        if (i + 3 < nCh) MCW_STAGE(i + 3, bo);      // refill just-freed buf

        #pragma unroll
        for (int k = 0; k < 4; ++k) {
            const float xw = (&xv.x)[k];
            const float lw = (&lv.x)[k];            // exactly 0.0f or 1.0f
            const float e  = __expf(-xw);
            const float r  = __builtin_amdgcn_rcpf(1.f + e);   // sigmoid
            const float s1 = e * r;                 // 1-sigmoid, no cancel
            const float sel = (lw != 0.f) ? r : s1;
            const float lg  = __logf(sel + MCW_EPS);
            ts[k] += r;
            sp[k]  = fmaf(lw, r, sp[k]);
            np[k] += lw;
            lsum  += lg;
            lp     = fmaf(lw, lg, lp);
        }
        bo = (bo == 2) ? 0 : bo + 1;
    }
#undef MCW_STAGE
#undef MCW_WAITV
#undef MCW_WAITL

    // ---- wave-reduce the global log sums ----
    #pragma unroll
    for (int o = 32; o > 0; o >>= 1) {
        lp   += __shfl_down(lp, o);
        lsum += __shfl_down(lsum, o);
    }
    if (ln == 0) { wl[0][wv] = lp; wl[1][wv] = lsum; }

    // ---- epilogue: reuse slab (all DMA drained by final vmcnt(0)) ----
    __syncthreads();
    float* red = slab;                 // [4][256] row-major

    #pragma unroll
    for (int k = 0; k < 4; ++k) red[(wv << 8) + c0 + k] = sp[k];
    __syncthreads();
    const float a = red[t] + red[256 + t] + red[512 + t] + red[768 + t];
    __syncthreads();

    #pragma unroll
    for (int k = 0; k < 4; ++k) red[(wv << 8) + c0 + k] = ts[k];
    __syncthreads();
    const float tsu = red[t] + red[256 + t] + red[512 + t] + red[768 + t];
    __syncthreads();

    #pragma unroll
    for (int k = 0; k < 4; ++k) red[(wv << 8) + c0 + k] = np[k];
    __syncthreads();
    const float d = red[t] + red[256 + t] + red[512 + t] + red[768 + t];

    // ---- coalesced partial writes (no atomics) ----
    const size_t base = (size_t)bid * 256;
    P_sp[base + t] = a;
    P_sn[base + t] = tsu - a;          // sum s over neg
    P_np[base + t] = d;
    if (t == 0) {
        const float L0 = wl[0][0] + wl[0][1] + wl[0][2] + wl[0][3];  // pos logs
        const float LS = wl[1][0] + wl[1][1] + wl[1][2] + wl[1][3];  // all logs
        P_lg[2 * bid + 0] = L0;
        P_lg[2 * bid + 1] = LS - L0;                                 // neg logs
    }
}

// ---------------------------------------------------------------------------
// Stage 2: fold G partials -> NRED partials, float4-vectorized.
// ---------------------------------------------------------------------------
__global__ __launch_bounds__(256) void mcwauc_reduce(
    const float* __restrict__ P_sp, const float* __restrict__ P_sn,
    const float* __restrict__ P_np,
    float* __restrict__ Q_sp, float* __restrict__ Q_sn, float* __restrict__ Q_np,
    int chunk)
{
    const int j  = blockIdx.x;
    const int t  = threadIdx.x;
    const int pr = t >> 6;              // row slice within chunk
    const int c4 = (t & 63) << 2;       // float4 column base
    float4 a = {0.f, 0.f, 0.f, 0.f}, b = a, d = a;
    for (int p = pr; p < chunk; p += 4) {
        const size_t off = ((size_t)j * chunk + p) * 256 + c4;
        const float4 va = *reinterpret_cast<const float4*>(P_sp + off);
        const float4 vb = *reinterpret_cast<const float4*>(P_sn + off);
        const float4 vd = *reinterpret_cast<const float4*>(P_np + off);
        a.x += va.x; a.y += va.y; a.z += va.z; a.w += va.w;
        b.x += vb.x; b.y += vb.y; b.z += vb.z; b.w += vb.w;
        d.x += vd.x; d.y += vd.y; d.z += vd.z; d.w += vd.w;
    }
    __shared__ float4 ra[4][64], rb[4][64], rd[4][64];
    ra[pr][t & 63] = a; rb[pr][t & 63] = b; rd[pr][t & 63] = d;
    __syncthreads();
    if (pr == 0) {
        #pragma unroll
        for (int r = 1; r < 4; ++r) {
            const float4 va = ra[r][t], vb = rb[r][t], vd = rd[r][t];
            a.x += va.x; a.y += va.y; a.z += va.z; a.w += va.w;
            b.x += vb.x; b.y += vb.y; b.z += vb.z; b.w += vb.w;
            d.x += vd.x; d.y += vd.y; d.z += vd.z; d.w += vd.w;
        }
        const size_t q = (size_t)j * 256 + c4;
        *reinterpret_cast<float4*>(Q_sp + q) = a;
        *reinterpret_cast<float4*>(Q_sn + q) = b;
        *reinterpret_cast<float4*>(Q_np + q) = d;
    }
}

// ---------------------------------------------------------------------------
// Stage 3: 1 block x 256 threads (one per column). Fold NRED partials,
// per-column penalty branch, CEL, write the 2 outputs.
// ---------------------------------------------------------------------------
__global__ __launch_bounds__(256) void mcwauc_fin(
    const float* __restrict__ Q_sp, const float* __restrict__ Q_sn,
    const float* __restrict__ Q_np, const float* __restrict__ P_lg,
    float* __restrict__ out, int B, int G)
{
    const int c = threadIdx.x;
    float a = 0.f, b = 0.f, d = 0.f;
    #pragma unroll 8
    for (int j = 0; j < NRED; ++j) {
        const size_t off = (size_t)j * 256 + c;
        a += Q_sp[off];
        b += Q_sn[off];
        d += Q_np[off];
    }
    float lp = 0.f, ln = 0.f;
    for (int p = c; p < G; p += 256) {
        lp += P_lg[2 * p + 0];
        ln += P_lg[2 * p + 1];
    }

    const float np = d;
    const float nn = (float)B - np;
    const float mp = a / fmaxf(np, 1.f);
    const float mn = b / fmaxf(nn, 1.f);

    float pen;
    if (np > 0.f && nn > 0.f)      pen = 1.f - mp + mn;
    else if (np == 0.f)            pen = 1.f + mn;
    else                           pen = 1.f - mp;

    // reduce {pen, np, lp, ln} across the 256 threads
    float psum = pen, csum = np;
    #pragma unroll
    for (int o = 32; o > 0; o >>= 1) {
        psum += __shfl_down(psum, o);
        csum += __shfl_down(csum, o);
        lp   += __shfl_down(lp, o);
        ln   += __shfl_down(ln, o);
    }
    __shared__ float s4[4][4];
    if ((c & 63) == 0) {
        s4[0][c >> 6] = psum;
        s4[1][c >> 6] = csum;
        s4[2][c >> 6] = lp;
        s4[3][c >> 6] = ln;
    }
    __syncthreads();

    if (c == 255) out[1] = 0.1f * pen;   // penalty term of the LAST category
    if (c == 0) {
        const double pensum = (double)s4[0][0] + s4[0][1] + s4[0][2] + s4[0][3];
        const double numP   = (double)s4[1][0] + s4[1][1] + s4[1][2] + s4[1][3];
        const double L0     = (double)s4[2][0] + s4[2][1] + s4[2][2] + s4[2][3];
        const double L1     = (double)s4[3][0] + s4[3][1] + s4[3][2] + s4[3][3];
        const double total  = (double)B * 256.0;
        const double aP = numP / total;
        const double aN = 1.0 - aP;
        const double cel = -aN * (L0 / total) - aP * (L1 / total);
        out[0] = (float)(cel + 0.1 * (pensum / 256.0));
    }
}

extern "C" void kernel_launch(void* const* d_in, const int* in_sizes, int n_in,
                              void* d_out, int out_size, void* d_ws, size_t ws_size,
                              hipStream_t stream) {
    const float* x = (const float*)d_in[0];
    const float* l = (const float*)d_in[1];
    const int n = in_sizes[0];
    const int B = n / 256;
    const int rowGroups = B / 4;           // B = 65536 -> 16384

    // G = stage-1 grid: 1536 = 6 blocks/CU at 24KB LDS; multiple of NRED.
    int G = 1536;
    auto need = [](int g) -> size_t {
        return (size_t)g * 768 * sizeof(float)       // P_sp/sn/np
             + (size_t)g * 2 * sizeof(float)         // P_lg
             + (size_t)NRED * 768 * sizeof(float);   // Q_sp/sn/np
    };
    while (G > NRED && need(G) > ws_size) G >>= 1;

    float* P_sp = (float*)d_ws;
    float* P_sn = P_sp + (size_t)G * 256;
    float* P_np = P_sn + (size_t)G * 256;
    float* P_lg = P_np + (size_t)G * 256;
    float* Q_sp = P_lg + (size_t)G * 2;
    float* Q_sn = Q_sp + (size_t)NRED * 256;
    float* Q_np = Q_sn + (size_t)NRED * 256;

    mcwauc_main<<<G, 256, 0, stream>>>(x, l, rowGroups,
                                       P_sp, P_sn, P_np, P_lg);
    mcwauc_reduce<<<NRED, 256, 0, stream>>>(P_sp, P_sn, P_np,
                                            Q_sp, Q_sn, Q_np, G / NRED);
    mcwauc_fin<<<1, 256, 0, stream>>>(Q_sp, Q_sn, Q_np, P_lg, (float*)d_out, B, G);
}